// Round 2
// baseline (1658.802 us; speedup 1.0000x reference)
//
#include <hip/hip_runtime.h>
#include <hip/hip_bf16.h>
#include <math.h>

#define BB   8
#define CC   256
#define HH   128
#define WW   128
#define MID  64
#define NPIX (HH * WW)          // 16384
#define BN_EPS 1e-5f

// LDS staging pitch/rows for 32x32-output-tile rotation kernels.
// Max input bbox span for a 31-px tile under any rotation: 31*sqrt(2)+3 < 48.
#define TPITCH 64
#define TROWS  48

// Table geometry: 4 angles x 2 dirs x 16 tiles x 1024 pixels
#define NTBL (4 * 2 * 16 * 1024)

__device__ __forceinline__ void rot_coords(int xx, int yy, float c, float s,
                                           int& x0, int& y0, float& wx1, float& wy1) {
    float X = -1.0f + (2.0f * (float)xx) / (float)(WW - 1);
    float Y = -1.0f + (2.0f * (float)yy) / (float)(HH - 1);
    float gx = c * X - s * Y;
    float gy = s * X + c * Y;
    float ix = (gx + 1.0f) * 0.5f * (float)(WW - 1);
    float iy = (gy + 1.0f) * 0.5f * (float)(HH - 1);
    float fx = floorf(ix), fy = floorf(iy);
    x0 = (int)fx; y0 = (int)fy;
    wx1 = ix - fx; wy1 = iy - fy;
}

__device__ __forceinline__ void rot_ixiy(float xx, float yy, float c, float s,
                                         float& ix, float& iy) {
    float X = -1.0f + (2.0f * xx) / (float)(WW - 1);
    float Y = -1.0f + (2.0f * yy) / (float)(HH - 1);
    float gx = c * X - s * Y;
    float gy = s * X + c * Y;
    ix = (gx + 1.0f) * 0.5f * (float)(WW - 1);
    iy = (gy + 1.0f) * 0.5f * (float)(HH - 1);
}

// Compute input-space bbox for a 32x32 output tile under rotation (c,s).
__device__ __forceinline__ void tile_bbox(int tx, int ty, float c, float s,
                                          int& x_lo, int& y_lo, int& bw, int& bh) {
    float ix00, iy00, ix10, iy10, ix01, iy01, ix11, iy11;
    rot_ixiy((float)tx,        (float)ty,        c, s, ix00, iy00);
    rot_ixiy((float)(tx + 31), (float)ty,        c, s, ix10, iy10);
    rot_ixiy((float)tx,        (float)(ty + 31), c, s, ix01, iy01);
    rot_ixiy((float)(tx + 31), (float)(ty + 31), c, s, ix11, iy11);
    float minix = fminf(fminf(ix00, ix10), fminf(ix01, ix11));
    float maxix = fmaxf(fmaxf(ix00, ix10), fmaxf(ix01, ix11));
    float miniy = fminf(fminf(iy00, iy10), fminf(iy01, iy11));
    float maxiy = fmaxf(fmaxf(iy00, iy10), fmaxf(iy01, iy11));
    x_lo = max((int)floorf(minix) - 1, 0);
    int x_hi = min((int)floorf(maxix) + 2, WW - 1);
    y_lo = max((int)floorf(miniy) - 1, 0);
    int y_hi = min((int)floorf(maxiy) + 2, HH - 1);
    x_hi = max(x_hi, x_lo);
    y_hi = max(y_hi, y_lo);
    bw = x_hi - x_lo + 1;   // <= 48
    bh = y_hi - y_lo + 1;
}

// Kernel 0 (once): precompute bilinear weights + clamped LDS offsets + bboxes.
__global__ void k_tables(const float* __restrict__ angles, float4* __restrict__ wtab,
                         ushort4* __restrict__ otab, int4* __restrict__ btab) {
    int blk  = blockIdx.x;            // (ai*2 + dir)*16 + tile, 128 blocks
    int tile = blk & 15;
    int dir  = (blk >> 4) & 1;
    int ai   = blk >> 5;
    float ang = angles[ai];
    float c = cosf(ang);
    float s = dir ? -sinf(ang) : sinf(ang);
    int ty = (tile >> 2) << 5;
    int tx = (tile & 3) << 5;

    int x_lo, y_lo, bw, bh;
    tile_bbox(tx, ty, c, s, x_lo, y_lo, bw, bh);

    for (int k = 0; k < 4; ++k) {
        int p = threadIdx.x + (k << 8);
        int yy = ty + (p >> 5);
        int xx = tx + (p & 31);
        int x0, y0; float wx1, wy1;
        rot_coords(xx, yy, c, s, x0, y0, wx1, wy1);
        int x1 = x0 + 1, y1 = y0 + 1;
        float wx0 = 1.f - wx1, wy0 = 1.f - wy1;
        bool vx0 = (unsigned)x0 < WW, vx1 = (unsigned)x1 < WW;
        bool vy0 = (unsigned)y0 < HH, vy1 = (unsigned)y1 < HH;
        float w00 = (vx0 && vy0) ? wx0 * wy0 : 0.f;
        float w10 = (vx1 && vy0) ? wx1 * wy0 : 0.f;
        float w01 = (vx0 && vy1) ? wx0 * wy1 : 0.f;
        float w11 = (vx1 && vy1) ? wx1 * wy1 : 0.f;
        int lx0 = min(max(x0 - x_lo, 0), bw - 1);
        int lx1 = min(max(x1 - x_lo, 0), bw - 1);
        int ly0 = min(max(y0 - y_lo, 0), bh - 1);
        int ly1 = min(max(y1 - y_lo, 0), bh - 1);
        int e = (blk << 10) + p;
        wtab[e] = make_float4(w00, w10, w01, w11);
        otab[e] = make_ushort4((unsigned short)(ly0 * TPITCH + lx0),
                               (unsigned short)(ly0 * TPITCH + lx1),
                               (unsigned short)(ly1 * TPITCH + lx0),
                               (unsigned short)(ly1 * TPITCH + lx1));
    }
    if (threadIdx.x == 0) btab[blk] = make_int4(x_lo, y_lo, bw, bh);
}

// Kernel 1: rotate 2 planes per block (tables amortized). Prefetch tables into
// registers BEFORE staging; staging is fixed-trip clamped loop so loads batch.
__global__ void k_rotate2(const float* __restrict__ x, const float4* __restrict__ wtab,
                          const ushort4* __restrict__ otab, const int4* __restrict__ btab,
                          int ai, __hip_bfloat16* __restrict__ xr, float* __restrict__ p_part) {
    __shared__ float lds[2][TROWS * TPITCH];
    __shared__ float red0[4], red1[4];

    int pair = blockIdx.x >> 4;
    int tile = blockIdx.x & 15;
    int plane0 = pair << 1;
    int ty = (tile >> 2) << 5;
    int tx = (tile & 3) << 5;
    int tb = (ai << 5) + tile;           // dir = 0

    const float4*  wt = wtab + ((size_t)tb << 10);
    const ushort4* ot = otab + ((size_t)tb << 10);
    float4 w[4]; ushort4 o[4];
    #pragma unroll
    for (int k = 0; k < 4; ++k) {
        int p = threadIdx.x + (k << 8);
        w[k] = wt[p]; o[k] = ot[p];
    }
    int4 bb = btab[tb];

    // stage: 128 threads per plane, 2 rows in flight, 24 fixed iterations
    int psel = threadIdx.x >> 7;
    int srow = (threadIdx.x >> 6) & 1;
    int scol = threadIdx.x & 63;
    const float* img = x + (size_t)(plane0 + psel) * NPIX;
    float* ldsp = lds[psel];
    #pragma unroll
    for (int i = 0; i < 24; ++i) {
        int r = srow + (i << 1);
        int gy = min(bb.y + r, HH - 1);
        int gx = min(bb.x + scol, WW - 1);
        ldsp[r * TPITCH + scol] = img[gy * WW + gx];
    }
    __syncthreads();

    __hip_bfloat16* op0 = xr + (size_t)plane0 * NPIX;
    __hip_bfloat16* op1 = op0 + NPIX;
    float ls0 = 0.f, ls1 = 0.f;
    #pragma unroll
    for (int k = 0; k < 4; ++k) {
        int p = threadIdx.x + (k << 8);
        float v0 = w[k].x * lds[0][o[k].x] + w[k].y * lds[0][o[k].y]
                 + w[k].z * lds[0][o[k].z] + w[k].w * lds[0][o[k].w];
        float v1 = w[k].x * lds[1][o[k].x] + w[k].y * lds[1][o[k].y]
                 + w[k].z * lds[1][o[k].z] + w[k].w * lds[1][o[k].w];
        int yy = ty + (p >> 5), xx = tx + (p & 31);
        op0[yy * WW + xx] = __float2bfloat16(v0);
        op1[yy * WW + xx] = __float2bfloat16(v1);
        ls0 += v0; ls1 += v1;
    }
    for (int off = 32; off; off >>= 1) {
        ls0 += __shfl_down(ls0, off, 64);
        ls1 += __shfl_down(ls1, off, 64);
    }
    if ((threadIdx.x & 63) == 0) { red0[threadIdx.x >> 6] = ls0; red1[threadIdx.x >> 6] = ls1; }
    __syncthreads();
    if (threadIdx.x == 0) {
        p_part[(size_t)plane0 * 16 + tile]       = red0[0] + red0[1] + red0[2] + red0[3];
        p_part[(size_t)(plane0 + 1) * 16 + tile] = red1[0] + red1[1] + red1[2] + red1[3];
    }
}

// Kernel 2: reduce p_part, tiny MLP. One block per batch (8 blocks).
__global__ void k_mlp(const float* __restrict__ p_part, const float* __restrict__ w1,
                      const float* __restrict__ g, const float* __restrict__ be,
                      const float* __restrict__ mu, const float* __restrict__ var,
                      const float* __restrict__ w2, float* __restrict__ ca) {
    __shared__ float sp[CC];
    __shared__ float sh[MID];
    int b = blockIdx.x;
    int t = threadIdx.x;

    const float* pr = p_part + (size_t)(b * CC + t) * 16;
    float acc = 0.f;
    for (int k = 0; k < 16; ++k) acc += pr[k];
    sp[t] = acc * (1.0f / (float)NPIX);
    __syncthreads();

    int m = t >> 2, q = t & 3;
    const float* w1r = w1 + m * CC + (q << 6);
    const float* spq = sp + (q << 6);
    float a = 0.f;
    for (int k = 0; k < 64; ++k) a += spq[k] * w1r[k];
    a += __shfl_xor(a, 1, 64);
    a += __shfl_xor(a, 2, 64);
    if (q == 0) {
        a = (a - mu[m]) * rsqrtf(var[m] + BN_EPS) * g[m] + be[m];
        sh[m] = fmaxf(a, 0.f);
    }
    __syncthreads();

    const float* w2r = w2 + t * MID;
    float a2 = 0.f;
    for (int k = 0; k < MID; ++k) a2 += sh[k] * w2r[k];
    ca[b * CC + t] = 1.f / (1.f + expf(-a2));
}

// Kernel 3: per-pixel channel avg & max of fca = xr * ca (4-way channel split).
__global__ void k_chanstat(const __hip_bfloat16* __restrict__ xr, const float* __restrict__ ca,
                           float* __restrict__ avg, float* __restrict__ mx) {
    __shared__ float rs0[4][64], rs1[4][64], rm0[4][64], rm1[4][64];
    int b    = blockIdx.x >> 7;
    int grp  = blockIdx.x & 127;
    int lane = threadIdx.x & 63;
    int cg   = threadIdx.x >> 6;
    int pp   = (grp << 6) + lane;

    const unsigned* xp = (const unsigned*)(xr + (size_t)b * CC * NPIX) + pp
                       + (size_t)(cg << 6) * (NPIX / 2);
    const float* cab = ca + b * CC + (cg << 6);

    float s0 = 0.f, s1 = 0.f, m0 = -INFINITY, m1 = -INFINITY;
    for (int ch = 0; ch < 64; ++ch) {
        unsigned u = xp[(size_t)ch * (NPIX / 2)];
        float v0 = __uint_as_float(u << 16);
        float v1 = __uint_as_float(u & 0xffff0000u);
        float cc = cab[ch];
        v0 *= cc; v1 *= cc;
        s0 += v0; s1 += v1;
        m0 = fmaxf(m0, v0); m1 = fmaxf(m1, v1);
    }
    rs0[cg][lane] = s0; rs1[cg][lane] = s1;
    rm0[cg][lane] = m0; rm1[cg][lane] = m1;
    __syncthreads();
    if (threadIdx.x < 64) {
        int l = threadIdx.x;
        float a0 = rs0[0][l] + rs0[1][l] + rs0[2][l] + rs0[3][l];
        float a1 = rs1[0][l] + rs1[1][l] + rs1[2][l] + rs1[3][l];
        float b0 = fmaxf(fmaxf(rm0[0][l], rm0[1][l]), fmaxf(rm0[2][l], rm0[3][l]));
        float b1 = fmaxf(fmaxf(rm1[0][l], rm1[1][l]), fmaxf(rm1[2][l], rm1[3][l]));
        float2* ap = (float2*)(avg + b * NPIX);
        float2* mp = (float2*)(mx + b * NPIX);
        int oidx = (grp << 6) + l;
        ap[oidx] = make_float2(a0 * (1.0f / (float)CC), a1 * (1.0f / (float)CC));
        mp[oidx] = make_float2(b0, b1);
    }
}

// Kernel 4: 7x7 conv (2 in-ch -> 1), pad 3, sigmoid -> sa.
__global__ void k_conv(const float* __restrict__ avg, const float* __restrict__ mx,
                       const float* __restrict__ w_sp, float* __restrict__ sa) {
    __shared__ float w[98];
    int t = threadIdx.x;
    if (t < 98) w[t] = w_sp[t];
    __syncthreads();
    int b = blockIdx.x >> 6;
    int pix = ((blockIdx.x & 63) << 8) + t;
    int yy = pix >> 7, xx = pix & (WW - 1);
    const float* a0 = avg + b * NPIX;
    const float* a1 = mx + b * NPIX;
    float acc = 0.f;
    for (int ky = 0; ky < 7; ++ky) {
        int ys = yy + ky - 3;
        if ((unsigned)ys >= HH) continue;
        for (int kx = 0; kx < 7; ++kx) {
            int xs = xx + kx - 3;
            if ((unsigned)xs >= WW) continue;
            acc += a0[ys * WW + xs] * w[ky * 7 + kx] + a1[ys * WW + xs] * w[49 + ky * 7 + kx];
        }
    }
    sa[b * NPIX + pix] = 1.f / (1.f + expf(-acc));
}

// Kernel 5a (pair-fused): inverse-rotate TWO angles, combine, write out once.
__global__ void k_invrot2(const __hip_bfloat16* __restrict__ xrA, const __hip_bfloat16* __restrict__ xrB,
                          const float* __restrict__ caA, const float* __restrict__ caB,
                          const float* __restrict__ saA, const float* __restrict__ saB,
                          const float4* __restrict__ wtab, const ushort4* __restrict__ otab,
                          const int4* __restrict__ btab,
                          int a0, int a1, int first, float* __restrict__ out) {
    __shared__ float lds[2][TROWS * TPITCH];

    int plane = blockIdx.x >> 4;
    int tile  = blockIdx.x & 15;
    int b = plane >> 8;
    int ty = (tile >> 2) << 5, tx = (tile & 3) << 5;
    int tbA = (a0 << 5) + 16 + tile;
    int tbB = (a1 << 5) + 16 + tile;

    const float4*  wtA = wtab + ((size_t)tbA << 10);
    const ushort4* otA = otab + ((size_t)tbA << 10);
    const float4*  wtB = wtab + ((size_t)tbB << 10);
    const ushort4* otB = otab + ((size_t)tbB << 10);
    float4 wA[4], wB[4]; ushort4 oA[4], oB[4];
    #pragma unroll
    for (int k = 0; k < 4; ++k) {
        int p = threadIdx.x + (k << 8);
        wA[k] = wtA[p]; oA[k] = otA[p];
        wB[k] = wtB[p]; oB[k] = otB[p];
    }
    int4 bbA = btab[tbA], bbB = btab[tbB];
    float scA = caA[plane] * 0.25f, scB = caB[plane] * 0.25f;

    // stage: 128 threads per angle (xr*sa product), 24 fixed iterations
    int asel = threadIdx.x >> 7;
    int srow = (threadIdx.x >> 6) & 1;
    int scol = threadIdx.x & 63;
    const __hip_bfloat16* xp = (asel ? xrB : xrA) + (size_t)plane * NPIX;
    const float* sp = (asel ? saB : saA) + b * NPIX;
    int4 bb = asel ? bbB : bbA;
    float* ldsp = lds[asel];
    #pragma unroll 8
    for (int i = 0; i < 24; ++i) {
        int r = srow + (i << 1);
        int gidx = min(bb.y + r, HH - 1) * WW + min(bb.x + scol, WW - 1);
        ldsp[r * TPITCH + scol] = __bfloat162float(xp[gidx]) * sp[gidx];
    }
    __syncthreads();

    float* op = out + (size_t)plane * NPIX;
    #pragma unroll
    for (int k = 0; k < 4; ++k) {
        int p = threadIdx.x + (k << 8);
        float v = scA * (wA[k].x * lds[0][oA[k].x] + wA[k].y * lds[0][oA[k].y]
                       + wA[k].z * lds[0][oA[k].z] + wA[k].w * lds[0][oA[k].w])
                + scB * (wB[k].x * lds[1][oB[k].x] + wB[k].y * lds[1][oB[k].y]
                       + wB[k].z * lds[1][oB[k].z] + wB[k].w * lds[1][oB[k].w]);
        int oi = (ty + (p >> 5)) * WW + tx + (p & 31);
        if (first) op[oi] = v;
        else       op[oi] += v;
    }
}

// Kernel 5b (fallback, single angle) — prefetch-style.
__global__ void k_invrot1(const __hip_bfloat16* __restrict__ xr, const float* __restrict__ ca,
                          const float* __restrict__ sa, const float4* __restrict__ wtab,
                          const ushort4* __restrict__ otab, const int4* __restrict__ btab,
                          int ai, int first, float* __restrict__ out) {
    __shared__ float lds[TROWS * TPITCH];

    int plane = blockIdx.x >> 4;
    int tile  = blockIdx.x & 15;
    int b = plane >> 8;
    int ty = (tile >> 2) << 5, tx = (tile & 3) << 5;
    int tb = (ai << 5) + 16 + tile;

    const float4*  wt = wtab + ((size_t)tb << 10);
    const ushort4* ot = otab + ((size_t)tb << 10);
    float4 w[4]; ushort4 o[4];
    #pragma unroll
    for (int k = 0; k < 4; ++k) {
        int p = threadIdx.x + (k << 8);
        w[k] = wt[p]; o[k] = ot[p];
    }
    int4 bb = btab[tb];
    float scale = ca[plane] * 0.25f;

    const __hip_bfloat16* xp = xr + (size_t)plane * NPIX;
    const float* sp = sa + b * NPIX;
    int srow = threadIdx.x >> 6;
    int scol = threadIdx.x & 63;
    #pragma unroll
    for (int i = 0; i < 12; ++i) {
        int r = srow + (i << 2);
        int gidx = min(bb.y + r, HH - 1) * WW + min(bb.x + scol, WW - 1);
        lds[r * TPITCH + scol] = __bfloat162float(xp[gidx]) * sp[gidx];
    }
    __syncthreads();

    float* op = out + (size_t)plane * NPIX;
    #pragma unroll
    for (int k = 0; k < 4; ++k) {
        int p = threadIdx.x + (k << 8);
        float v = w[k].x * lds[o[k].x] + w[k].y * lds[o[k].y]
                + w[k].z * lds[o[k].z] + w[k].w * lds[o[k].w];
        float ov = v * scale;
        int oi = (ty + (p >> 5)) * WW + tx + (p & 31);
        if (first) op[oi] = ov;
        else       op[oi] += ov;
    }
}

extern "C" void kernel_launch(void* const* d_in, const int* in_sizes, int n_in,
                              void* d_out, int out_size, void* d_ws, size_t ws_size,
                              hipStream_t stream) {
    const float* x      = (const float*)d_in[0];
    const float* angles = (const float*)d_in[1];
    const float* w1     = (const float*)d_in[2];
    const float* gmm    = (const float*)d_in[3];
    const float* bet    = (const float*)d_in[4];
    const float* mu     = (const float*)d_in[5];
    const float* var    = (const float*)d_in[6];
    const float* w2     = (const float*)d_in[7];
    const float* wsp    = (const float*)d_in[8];
    float* out = (float*)d_out;

    char* ws = (char*)d_ws;
    float4*  wtab = (float4*)ws;                         // 2 MiB, 16B-aligned at ws base
    ushort4* otab = (ushort4*)(wtab + NTBL);             // 1 MiB
    int4*    btab = (int4*)(otab + NTBL);                // 2 KiB
    float* p_part = (float*)(btab + 128);                // 128 KiB
    float* caA = p_part + BB * CC * 16;
    float* caB = caA + BB * CC;
    float* avg = caB + BB * CC;
    float* mx  = avg + BB * NPIX;
    float* saA = mx + BB * NPIX;
    float* saB = saA + BB * NPIX;
    __hip_bfloat16* xrA = (__hip_bfloat16*)(saB + BB * NPIX);     // 64 MiB
    __hip_bfloat16* xrB = xrA + (size_t)BB * CC * NPIX;           // 64 MiB
    size_t need_pair = (size_t)((char*)(xrB + (size_t)BB * CC * NPIX) - ws);

    k_tables<<<128, 256, 0, stream>>>(angles, wtab, otab, btab);

    if (ws_size >= need_pair) {
        // Pair-fused: out written/accumulated once per 2 angles (RMW halved).
        for (int pr = 0; pr < 2; ++pr) {
            int a0 = pr * 2, a1 = a0 + 1;
            k_rotate2 <<<BB * CC * 8, 256, 0, stream>>>(x, wtab, otab, btab, a0, xrA, p_part);
            k_mlp     <<<BB, 256, 0, stream>>>(p_part, w1, gmm, bet, mu, var, w2, caA);
            k_chanstat<<<BB * 128, 256, 0, stream>>>(xrA, caA, avg, mx);
            k_conv    <<<BB * 64, 256, 0, stream>>>(avg, mx, wsp, saA);
            k_rotate2 <<<BB * CC * 8, 256, 0, stream>>>(x, wtab, otab, btab, a1, xrB, p_part);
            k_mlp     <<<BB, 256, 0, stream>>>(p_part, w1, gmm, bet, mu, var, w2, caB);
            k_chanstat<<<BB * 128, 256, 0, stream>>>(xrB, caB, avg, mx);
            k_conv    <<<BB * 64, 256, 0, stream>>>(avg, mx, wsp, saB);
            k_invrot2 <<<BB * CC * 16, 256, 0, stream>>>(xrA, xrB, caA, caB, saA, saB,
                                                         wtab, otab, btab, a0, a1, pr == 0, out);
        }
    } else {
        // Fallback: single xr buffer, per-angle accumulate.
        for (int ai = 0; ai < 4; ++ai) {
            k_rotate2 <<<BB * CC * 8, 256, 0, stream>>>(x, wtab, otab, btab, ai, xrA, p_part);
            k_mlp     <<<BB, 256, 0, stream>>>(p_part, w1, gmm, bet, mu, var, w2, caA);
            k_chanstat<<<BB * 128, 256, 0, stream>>>(xrA, caA, avg, mx);
            k_conv    <<<BB * 64, 256, 0, stream>>>(avg, mx, wsp, saA);
            k_invrot1 <<<BB * CC * 16, 256, 0, stream>>>(xrA, caA, saA, wtab, otab, btab,
                                                         ai, ai == 0, out);
        }
    }
}

// Round 4
// 928.801 us; speedup vs baseline: 1.7860x; 1.7860x over previous
//
#include <hip/hip_runtime.h>
#include <hip/hip_bf16.h>
#include <math.h>

#define BB   8
#define CC   256
#define HH   128
#define WW   128
#define MID  64
#define NPIX (HH * WW)          // 16384
#define BN_EPS 1e-5f

// LDS staging pitch/rows for 32x32-output-tile rotation kernels.
// Max input bbox span for a 31-px tile under any rotation: 31*sqrt(2)+3 < 48.
// TPITCH=57 (odd): 57 mod 32 = 25, coprime with 32 -> the 90-degree gather
// (lane stride = TPITCH) spreads across all 32 banks, 2 lanes/bank (free).
// Staging writes MUST be guarded to scol < 56: cols 57..63 of row r would
// alias cols 0..6 of row r+1 (that race was round 3's correctness bug).
#define TPITCH 57
#define TROWS  48

// Table geometry: 4 angles x 2 dirs x 16 tiles x 1024 pixels
#define NTBL (4 * 2 * 16 * 1024)

__device__ __forceinline__ void rot_coords(int xx, int yy, float c, float s,
                                           int& x0, int& y0, float& wx1, float& wy1) {
    float X = -1.0f + (2.0f * (float)xx) / (float)(WW - 1);
    float Y = -1.0f + (2.0f * (float)yy) / (float)(HH - 1);
    float gx = c * X - s * Y;
    float gy = s * X + c * Y;
    float ix = (gx + 1.0f) * 0.5f * (float)(WW - 1);
    float iy = (gy + 1.0f) * 0.5f * (float)(HH - 1);
    float fx = floorf(ix), fy = floorf(iy);
    x0 = (int)fx; y0 = (int)fy;
    wx1 = ix - fx; wy1 = iy - fy;
}

__device__ __forceinline__ void rot_ixiy(float xx, float yy, float c, float s,
                                         float& ix, float& iy) {
    float X = -1.0f + (2.0f * xx) / (float)(WW - 1);
    float Y = -1.0f + (2.0f * yy) / (float)(HH - 1);
    float gx = c * X - s * Y;
    float gy = s * X + c * Y;
    ix = (gx + 1.0f) * 0.5f * (float)(WW - 1);
    iy = (gy + 1.0f) * 0.5f * (float)(HH - 1);
}

// Compute input-space bbox for a 32x32 output tile under rotation (c,s).
__device__ __forceinline__ void tile_bbox(int tx, int ty, float c, float s,
                                          int& x_lo, int& y_lo, int& bw, int& bh) {
    float ix00, iy00, ix10, iy10, ix01, iy01, ix11, iy11;
    rot_ixiy((float)tx,        (float)ty,        c, s, ix00, iy00);
    rot_ixiy((float)(tx + 31), (float)ty,        c, s, ix10, iy10);
    rot_ixiy((float)tx,        (float)(ty + 31), c, s, ix01, iy01);
    rot_ixiy((float)(tx + 31), (float)(ty + 31), c, s, ix11, iy11);
    float minix = fminf(fminf(ix00, ix10), fminf(ix01, ix11));
    float maxix = fmaxf(fmaxf(ix00, ix10), fmaxf(ix01, ix11));
    float miniy = fminf(fminf(iy00, iy10), fminf(iy01, iy11));
    float maxiy = fmaxf(fmaxf(iy00, iy10), fmaxf(iy01, iy11));
    x_lo = max((int)floorf(minix) - 1, 0);
    int x_hi = min((int)floorf(maxix) + 2, WW - 1);
    y_lo = max((int)floorf(miniy) - 1, 0);
    int y_hi = min((int)floorf(maxiy) + 2, HH - 1);
    x_hi = max(x_hi, x_lo);
    y_hi = max(y_hi, y_lo);
    bw = x_hi - x_lo + 1;   // <= 48
    bh = y_hi - y_lo + 1;
}

// Kernel 0 (once): precompute bilinear weights + clamped LDS offsets + bboxes.
__global__ void k_tables(const float* __restrict__ angles, float4* __restrict__ wtab,
                         ushort4* __restrict__ otab, int4* __restrict__ btab) {
    int blk  = blockIdx.x;            // (ai*2 + dir)*16 + tile, 128 blocks
    int tile = blk & 15;
    int dir  = (blk >> 4) & 1;
    int ai   = blk >> 5;
    float ang = angles[ai];
    float c = cosf(ang);
    float s = dir ? -sinf(ang) : sinf(ang);
    int ty = (tile >> 2) << 5;
    int tx = (tile & 3) << 5;

    int x_lo, y_lo, bw, bh;
    tile_bbox(tx, ty, c, s, x_lo, y_lo, bw, bh);

    for (int k = 0; k < 4; ++k) {
        int p = threadIdx.x + (k << 8);
        int yy = ty + (p >> 5);
        int xx = tx + (p & 31);
        int x0, y0; float wx1, wy1;
        rot_coords(xx, yy, c, s, x0, y0, wx1, wy1);
        int x1 = x0 + 1, y1 = y0 + 1;
        float wx0 = 1.f - wx1, wy0 = 1.f - wy1;
        bool vx0 = (unsigned)x0 < WW, vx1 = (unsigned)x1 < WW;
        bool vy0 = (unsigned)y0 < HH, vy1 = (unsigned)y1 < HH;
        float w00 = (vx0 && vy0) ? wx0 * wy0 : 0.f;
        float w10 = (vx1 && vy0) ? wx1 * wy0 : 0.f;
        float w01 = (vx0 && vy1) ? wx0 * wy1 : 0.f;
        float w11 = (vx1 && vy1) ? wx1 * wy1 : 0.f;
        int lx0 = min(max(x0 - x_lo, 0), bw - 1);
        int lx1 = min(max(x1 - x_lo, 0), bw - 1);
        int ly0 = min(max(y0 - y_lo, 0), bh - 1);
        int ly1 = min(max(y1 - y_lo, 0), bh - 1);
        int e = (blk << 10) + p;
        wtab[e] = make_float4(w00, w10, w01, w11);
        otab[e] = make_ushort4((unsigned short)(ly0 * TPITCH + lx0),
                               (unsigned short)(ly0 * TPITCH + lx1),
                               (unsigned short)(ly1 * TPITCH + lx0),
                               (unsigned short)(ly1 * TPITCH + lx1));
    }
    if (threadIdx.x == 0) btab[blk] = make_int4(x_lo, y_lo, bw, bh);
}

// Kernel 1: rotate 2 planes per block (tables amortized). Tables prefetched to
// registers; staging is fixed-trip, clamped to the BBOX (duplicate loads land
// on already-fetched lines); LDS write guarded to scol<56 (pitch-57 rows).
__global__ void k_rotate2(const float* __restrict__ x, const float4* __restrict__ wtab,
                          const ushort4* __restrict__ otab, const int4* __restrict__ btab,
                          int ai, __hip_bfloat16* __restrict__ xr, float* __restrict__ p_part) {
    __shared__ float lds[2][TROWS * TPITCH];
    __shared__ float red0[4], red1[4];

    int pair = blockIdx.x >> 4;
    int tile = blockIdx.x & 15;
    int plane0 = pair << 1;
    int ty = (tile >> 2) << 5;
    int tx = (tile & 3) << 5;
    int tb = (ai << 5) + tile;           // dir = 0

    const float4*  wt = wtab + ((size_t)tb << 10);
    const ushort4* ot = otab + ((size_t)tb << 10);
    float4 w[4]; ushort4 o[4];
    #pragma unroll
    for (int k = 0; k < 4; ++k) {
        int p = threadIdx.x + (k << 8);
        w[k] = wt[p]; o[k] = ot[p];
    }
    int4 bb = btab[tb];

    // stage: 128 threads per plane, rows srow+2i, clamped to bbox.
    int psel = threadIdx.x >> 7;
    int srow = (threadIdx.x >> 6) & 1;
    int scol = threadIdx.x & 63;
    const float* img = x + (size_t)(plane0 + psel) * NPIX;
    float* ldsp = lds[psel];
    int gx = bb.x + min(scol, bb.z - 1);
    bool wr = scol < 56;                 // cols 56..63 never read (bw <= 48)
    #pragma unroll
    for (int i = 0; i < 24; ++i) {
        int r = srow + (i << 1);
        int gy = bb.y + min(r, bb.w - 1);
        float v = img[gy * WW + gx];
        if (wr) ldsp[r * TPITCH + scol] = v;
    }
    __syncthreads();

    __hip_bfloat16* op0 = xr + (size_t)plane0 * NPIX;
    __hip_bfloat16* op1 = op0 + NPIX;
    float ls0 = 0.f, ls1 = 0.f;
    #pragma unroll
    for (int k = 0; k < 4; ++k) {
        int p = threadIdx.x + (k << 8);
        float v0 = w[k].x * lds[0][o[k].x] + w[k].y * lds[0][o[k].y]
                 + w[k].z * lds[0][o[k].z] + w[k].w * lds[0][o[k].w];
        float v1 = w[k].x * lds[1][o[k].x] + w[k].y * lds[1][o[k].y]
                 + w[k].z * lds[1][o[k].z] + w[k].w * lds[1][o[k].w];
        int yy = ty + (p >> 5), xx = tx + (p & 31);
        op0[yy * WW + xx] = __float2bfloat16(v0);
        op1[yy * WW + xx] = __float2bfloat16(v1);
        ls0 += v0; ls1 += v1;
    }
    for (int off = 32; off; off >>= 1) {
        ls0 += __shfl_down(ls0, off, 64);
        ls1 += __shfl_down(ls1, off, 64);
    }
    if ((threadIdx.x & 63) == 0) { red0[threadIdx.x >> 6] = ls0; red1[threadIdx.x >> 6] = ls1; }
    __syncthreads();
    if (threadIdx.x == 0) {
        p_part[(size_t)plane0 * 16 + tile]       = red0[0] + red0[1] + red0[2] + red0[3];
        p_part[(size_t)(plane0 + 1) * 16 + tile] = red1[0] + red1[1] + red1[2] + red1[3];
    }
}

// Kernel 2: reduce p_part, tiny MLP. One block per batch (8 blocks).
__global__ void k_mlp(const float* __restrict__ p_part, const float* __restrict__ w1,
                      const float* __restrict__ g, const float* __restrict__ be,
                      const float* __restrict__ mu, const float* __restrict__ var,
                      const float* __restrict__ w2, float* __restrict__ ca) {
    __shared__ float sp[CC];
    __shared__ float sh[MID];
    int b = blockIdx.x;
    int t = threadIdx.x;

    const float* pr = p_part + (size_t)(b * CC + t) * 16;
    float acc = 0.f;
    for (int k = 0; k < 16; ++k) acc += pr[k];
    sp[t] = acc * (1.0f / (float)NPIX);
    __syncthreads();

    int m = t >> 2, q = t & 3;
    const float* w1r = w1 + m * CC + (q << 6);
    const float* spq = sp + (q << 6);
    float a = 0.f;
    for (int k = 0; k < 64; ++k) a += spq[k] * w1r[k];
    a += __shfl_xor(a, 1, 64);
    a += __shfl_xor(a, 2, 64);
    if (q == 0) {
        a = (a - mu[m]) * rsqrtf(var[m] + BN_EPS) * g[m] + be[m];
        sh[m] = fmaxf(a, 0.f);
    }
    __syncthreads();

    const float* w2r = w2 + t * MID;
    float a2 = 0.f;
    for (int k = 0; k < MID; ++k) a2 += sh[k] * w2r[k];
    ca[b * CC + t] = 1.f / (1.f + expf(-a2));
}

// Kernel 3: per-pixel channel avg & max of fca = xr * ca (4-way channel split).
__global__ void k_chanstat(const __hip_bfloat16* __restrict__ xr, const float* __restrict__ ca,
                           float* __restrict__ avg, float* __restrict__ mx) {
    __shared__ float rs0[4][64], rs1[4][64], rm0[4][64], rm1[4][64];
    int b    = blockIdx.x >> 7;
    int grp  = blockIdx.x & 127;
    int lane = threadIdx.x & 63;
    int cg   = threadIdx.x >> 6;
    int pp   = (grp << 6) + lane;

    const unsigned* xp = (const unsigned*)(xr + (size_t)b * CC * NPIX) + pp
                       + (size_t)(cg << 6) * (NPIX / 2);
    const float* cab = ca + b * CC + (cg << 6);

    float s0 = 0.f, s1 = 0.f, m0 = -INFINITY, m1 = -INFINITY;
    for (int ch = 0; ch < 64; ++ch) {
        unsigned u = xp[(size_t)ch * (NPIX / 2)];
        float v0 = __uint_as_float(u << 16);
        float v1 = __uint_as_float(u & 0xffff0000u);
        float cc = cab[ch];
        v0 *= cc; v1 *= cc;
        s0 += v0; s1 += v1;
        m0 = fmaxf(m0, v0); m1 = fmaxf(m1, v1);
    }
    rs0[cg][lane] = s0; rs1[cg][lane] = s1;
    rm0[cg][lane] = m0; rm1[cg][lane] = m1;
    __syncthreads();
    if (threadIdx.x < 64) {
        int l = threadIdx.x;
        float a0 = rs0[0][l] + rs0[1][l] + rs0[2][l] + rs0[3][l];
        float a1 = rs1[0][l] + rs1[1][l] + rs1[2][l] + rs1[3][l];
        float b0 = fmaxf(fmaxf(rm0[0][l], rm0[1][l]), fmaxf(rm0[2][l], rm0[3][l]));
        float b1 = fmaxf(fmaxf(rm1[0][l], rm1[1][l]), fmaxf(rm1[2][l], rm1[3][l]));
        float2* ap = (float2*)(avg + b * NPIX);
        float2* mp = (float2*)(mx + b * NPIX);
        int oidx = (grp << 6) + l;
        ap[oidx] = make_float2(a0 * (1.0f / (float)CC), a1 * (1.0f / (float)CC));
        mp[oidx] = make_float2(b0, b1);
    }
}

// Kernel 4: 7x7 conv (2 in-ch -> 1), pad 3, sigmoid -> sa.
__global__ void k_conv(const float* __restrict__ avg, const float* __restrict__ mx,
                       const float* __restrict__ w_sp, float* __restrict__ sa) {
    __shared__ float w[98];
    int t = threadIdx.x;
    if (t < 98) w[t] = w_sp[t];
    __syncthreads();
    int b = blockIdx.x >> 6;
    int pix = ((blockIdx.x & 63) << 8) + t;
    int yy = pix >> 7, xx = pix & (WW - 1);
    const float* a0 = avg + b * NPIX;
    const float* a1 = mx + b * NPIX;
    float acc = 0.f;
    for (int ky = 0; ky < 7; ++ky) {
        int ys = yy + ky - 3;
        if ((unsigned)ys >= HH) continue;
        for (int kx = 0; kx < 7; ++kx) {
            int xs = xx + kx - 3;
            if ((unsigned)xs >= WW) continue;
            acc += a0[ys * WW + xs] * w[ky * 7 + kx] + a1[ys * WW + xs] * w[49 + ky * 7 + kx];
        }
    }
    sa[b * NPIX + pix] = 1.f / (1.f + expf(-acc));
}

// Kernel 5a (pair-fused): inverse-rotate TWO angles, combine, write out once.
__global__ void k_invrot2(const __hip_bfloat16* __restrict__ xrA, const __hip_bfloat16* __restrict__ xrB,
                          const float* __restrict__ caA, const float* __restrict__ caB,
                          const float* __restrict__ saA, const float* __restrict__ saB,
                          const float4* __restrict__ wtab, const ushort4* __restrict__ otab,
                          const int4* __restrict__ btab,
                          int a0, int a1, int first, float* __restrict__ out) {
    __shared__ float lds[2][TROWS * TPITCH];

    int plane = blockIdx.x >> 4;
    int tile  = blockIdx.x & 15;
    int b = plane >> 8;
    int ty = (tile >> 2) << 5, tx = (tile & 3) << 5;
    int tbA = (a0 << 5) + 16 + tile;
    int tbB = (a1 << 5) + 16 + tile;

    const float4*  wtA = wtab + ((size_t)tbA << 10);
    const ushort4* otA = otab + ((size_t)tbA << 10);
    const float4*  wtB = wtab + ((size_t)tbB << 10);
    const ushort4* otB = otab + ((size_t)tbB << 10);
    float4 wA[4], wB[4]; ushort4 oA[4], oB[4];
    #pragma unroll
    for (int k = 0; k < 4; ++k) {
        int p = threadIdx.x + (k << 8);
        wA[k] = wtA[p]; oA[k] = otA[p];
        wB[k] = wtB[p]; oB[k] = otB[p];
    }
    int4 bbA = btab[tbA], bbB = btab[tbB];
    float scA = caA[plane] * 0.25f, scB = caB[plane] * 0.25f;

    // stage: 128 threads per angle (xr*sa product), clamped to bbox.
    int asel = threadIdx.x >> 7;
    int srow = (threadIdx.x >> 6) & 1;
    int scol = threadIdx.x & 63;
    const __hip_bfloat16* xp = (asel ? xrB : xrA) + (size_t)plane * NPIX;
    const float* sp = (asel ? saB : saA) + b * NPIX;
    int4 bb = asel ? bbB : bbA;
    float* ldsp = lds[asel];
    int gx = bb.x + min(scol, bb.z - 1);
    bool wr = scol < 56;                 // cols 56..63 never read (bw <= 48)
    #pragma unroll 8
    for (int i = 0; i < 24; ++i) {
        int r = srow + (i << 1);
        int gidx = (bb.y + min(r, bb.w - 1)) * WW + gx;
        float v = __bfloat162float(xp[gidx]) * sp[gidx];
        if (wr) ldsp[r * TPITCH + scol] = v;
    }
    __syncthreads();

    float* op = out + (size_t)plane * NPIX;
    #pragma unroll
    for (int k = 0; k < 4; ++k) {
        int p = threadIdx.x + (k << 8);
        float v = scA * (wA[k].x * lds[0][oA[k].x] + wA[k].y * lds[0][oA[k].y]
                       + wA[k].z * lds[0][oA[k].z] + wA[k].w * lds[0][oA[k].w])
                + scB * (wB[k].x * lds[1][oB[k].x] + wB[k].y * lds[1][oB[k].y]
                       + wB[k].z * lds[1][oB[k].z] + wB[k].w * lds[1][oB[k].w]);
        int oi = (ty + (p >> 5)) * WW + tx + (p & 31);
        if (first) op[oi] = v;
        else       op[oi] += v;
    }
}

// Kernel 5b (fallback, single angle) — prefetch-style.
__global__ void k_invrot1(const __hip_bfloat16* __restrict__ xr, const float* __restrict__ ca,
                          const float* __restrict__ sa, const float4* __restrict__ wtab,
                          const ushort4* __restrict__ otab, const int4* __restrict__ btab,
                          int ai, int first, float* __restrict__ out) {
    __shared__ float lds[TROWS * TPITCH];

    int plane = blockIdx.x >> 4;
    int tile  = blockIdx.x & 15;
    int b = plane >> 8;
    int ty = (tile >> 2) << 5, tx = (tile & 3) << 5;
    int tb = (ai << 5) + 16 + tile;

    const float4*  wt = wtab + ((size_t)tb << 10);
    const ushort4* ot = otab + ((size_t)tb << 10);
    float4 w[4]; ushort4 o[4];
    #pragma unroll
    for (int k = 0; k < 4; ++k) {
        int p = threadIdx.x + (k << 8);
        w[k] = wt[p]; o[k] = ot[p];
    }
    int4 bb = btab[tb];
    float scale = ca[plane] * 0.25f;

    const __hip_bfloat16* xp = xr + (size_t)plane * NPIX;
    const float* sp = sa + b * NPIX;
    int srow = threadIdx.x >> 6;
    int scol = threadIdx.x & 63;
    int gx = bb.x + min(scol, bb.z - 1);
    bool wr = scol < 56;
    #pragma unroll
    for (int i = 0; i < 12; ++i) {
        int r = srow + (i << 2);
        int gidx = (bb.y + min(r, bb.w - 1)) * WW + gx;
        float v = __bfloat162float(xp[gidx]) * sp[gidx];
        if (wr) lds[r * TPITCH + scol] = v;
    }
    __syncthreads();

    float* op = out + (size_t)plane * NPIX;
    #pragma unroll
    for (int k = 0; k < 4; ++k) {
        int p = threadIdx.x + (k << 8);
        float v = w[k].x * lds[o[k].x] + w[k].y * lds[o[k].y]
                + w[k].z * lds[o[k].z] + w[k].w * lds[o[k].w];
        float ov = v * scale;
        int oi = (ty + (p >> 5)) * WW + tx + (p & 31);
        if (first) op[oi] = ov;
        else       op[oi] += ov;
    }
}

extern "C" void kernel_launch(void* const* d_in, const int* in_sizes, int n_in,
                              void* d_out, int out_size, void* d_ws, size_t ws_size,
                              hipStream_t stream) {
    const float* x      = (const float*)d_in[0];
    const float* angles = (const float*)d_in[1];
    const float* w1     = (const float*)d_in[2];
    const float* gmm    = (const float*)d_in[3];
    const float* bet    = (const float*)d_in[4];
    const float* mu     = (const float*)d_in[5];
    const float* var    = (const float*)d_in[6];
    const float* w2     = (const float*)d_in[7];
    const float* wsp    = (const float*)d_in[8];
    float* out = (float*)d_out;

    char* ws = (char*)d_ws;
    float4*  wtab = (float4*)ws;                         // 2 MiB, 16B-aligned at ws base
    ushort4* otab = (ushort4*)(wtab + NTBL);             // 1 MiB
    int4*    btab = (int4*)(otab + NTBL);                // 2 KiB
    float* p_part = (float*)(btab + 128);                // 128 KiB
    float* caA = p_part + BB * CC * 16;
    float* caB = caA + BB * CC;
    float* avg = caB + BB * CC;
    float* mx  = avg + BB * NPIX;
    float* saA = mx + BB * NPIX;
    float* saB = saA + BB * NPIX;
    __hip_bfloat16* xrA = (__hip_bfloat16*)(saB + BB * NPIX);     // 64 MiB
    __hip_bfloat16* xrB = xrA + (size_t)BB * CC * NPIX;           // 64 MiB
    size_t need_pair = (size_t)((char*)(xrB + (size_t)BB * CC * NPIX) - ws);

    k_tables<<<128, 256, 0, stream>>>(angles, wtab, otab, btab);

    if (ws_size >= need_pair) {
        // Pair-fused: out written/accumulated once per 2 angles (RMW halved).
        for (int pr = 0; pr < 2; ++pr) {
            int a0 = pr * 2, a1 = a0 + 1;
            k_rotate2 <<<BB * CC * 8, 256, 0, stream>>>(x, wtab, otab, btab, a0, xrA, p_part);
            k_mlp     <<<BB, 256, 0, stream>>>(p_part, w1, gmm, bet, mu, var, w2, caA);
            k_chanstat<<<BB * 128, 256, 0, stream>>>(xrA, caA, avg, mx);
            k_conv    <<<BB * 64, 256, 0, stream>>>(avg, mx, wsp, saA);
            k_rotate2 <<<BB * CC * 8, 256, 0, stream>>>(x, wtab, otab, btab, a1, xrB, p_part);
            k_mlp     <<<BB, 256, 0, stream>>>(p_part, w1, gmm, bet, mu, var, w2, caB);
            k_chanstat<<<BB * 128, 256, 0, stream>>>(xrB, caB, avg, mx);
            k_conv    <<<BB * 64, 256, 0, stream>>>(avg, mx, wsp, saB);
            k_invrot2 <<<BB * CC * 16, 256, 0, stream>>>(xrA, xrB, caA, caB, saA, saB,
                                                         wtab, otab, btab, a0, a1, pr == 0, out);
        }
    } else {
        // Fallback: single xr buffer, per-angle accumulate.
        for (int ai = 0; ai < 4; ++ai) {
            k_rotate2 <<<BB * CC * 8, 256, 0, stream>>>(x, wtab, otab, btab, ai, xrA, p_part);
            k_mlp     <<<BB, 256, 0, stream>>>(p_part, w1, gmm, bet, mu, var, w2, caA);
            k_chanstat<<<BB * 128, 256, 0, stream>>>(xrA, caA, avg, mx);
            k_conv    <<<BB * 64, 256, 0, stream>>>(avg, mx, wsp, saA);
            k_invrot1 <<<BB * CC * 16, 256, 0, stream>>>(xrA, caA, saA, wtab, otab, btab,
                                                         ai, ai == 0, out);
        }
    }
}

// Round 5
// 838.287 us; speedup vs baseline: 1.9788x; 1.1080x over previous
//
#include <hip/hip_runtime.h>
#include <hip/hip_bf16.h>
#include <math.h>

#define BB   8
#define CC   256
#define HH   128
#define WW   128
#define MID  64
#define NPIX (HH * WW)          // 16384
#define BN_EPS 1e-5f

__device__ __forceinline__ void rot_coords(int xx, int yy, float c, float s,
                                           int& x0, int& y0, float& wx1, float& wy1) {
    float X = -1.0f + (2.0f * (float)xx) / (float)(WW - 1);
    float Y = -1.0f + (2.0f * (float)yy) / (float)(HH - 1);
    float gx = c * X - s * Y;
    float gy = s * X + c * Y;
    float ix = (gx + 1.0f) * 0.5f * (float)(WW - 1);
    float iy = (gy + 1.0f) * 0.5f * (float)(HH - 1);
    float fx = floorf(ix), fy = floorf(iy);
    x0 = (int)fx; y0 = (int)fy;
    wx1 = ix - fx; wy1 = iy - fy;
}

// Compute 4-tap bilinear weights (validity folded in) + clamped coords.
__device__ __forceinline__ void taps(int xx, int yy, float c, float s,
                                     float& w00, float& w10, float& w01, float& w11,
                                     int& lx0, int& lx1, int& ly0, int& ly1) {
    int x0, y0; float wx1, wy1;
    rot_coords(xx, yy, c, s, x0, y0, wx1, wy1);
    int x1 = x0 + 1, y1 = y0 + 1;
    float wx0 = 1.f - wx1, wy0 = 1.f - wy1;
    bool vx0 = (unsigned)x0 < WW, vx1 = (unsigned)x1 < WW;
    bool vy0 = (unsigned)y0 < HH, vy1 = (unsigned)y1 < HH;
    w00 = (vx0 && vy0) ? wx0 * wy0 : 0.f;
    w10 = (vx1 && vy0) ? wx1 * wy0 : 0.f;
    w01 = (vx0 && vy1) ? wx0 * wy1 : 0.f;
    w11 = (vx1 && vy1) ? wx1 * wy1 : 0.f;
    lx0 = min(max(x0, 0), WW - 1); lx1 = min(max(x1, 0), WW - 1);
    ly0 = min(max(y0, 0), HH - 1); ly1 = min(max(y1, 0), HH - 1);
}

__device__ __forceinline__ unsigned q16(float w) {   // unorm16 quantize
    return (unsigned)(w * 65535.f + 0.5f);
}

// Kernel 0 (once): whole-plane gather tables, u16-packed, LDS offsets pre-swizzled.
// dir 0 (rotate, fp32 LDS):  e = ly*128 + (lx ^ (ly&31))               [word swizzle]
// dir 1 (invrot, bf16 LDS):  e = ly*128 + (((lx>>1)^(ly&31))<<1)|(lx&1) [u32-pair swizzle]
__global__ __launch_bounds__(512) void k_tables(const float* __restrict__ angles,
                                                uint4* __restrict__ ttab,
                                                uint2* __restrict__ oinv) {
    int dir = blockIdx.x & 1, ai = blockIdx.x >> 1;
    float ang = angles[ai];
    float c = cosf(ang), s = dir ? -sinf(ang) : sinf(ang);
    for (int i = 0; i < 32; ++i) {
        int px = (i << 9) + threadIdx.x;
        int yy = px >> 7, xx = px & 127;
        float w00, w10, w01, w11; int lx0, lx1, ly0, ly1;
        taps(xx, yy, c, s, w00, w10, w01, w11, lx0, lx1, ly0, ly1);
        if (dir == 0) {
            unsigned e00 = ly0 * 128 + (lx0 ^ (ly0 & 31));
            unsigned e10 = ly0 * 128 + (lx1 ^ (ly0 & 31));
            unsigned e01 = ly1 * 128 + (lx0 ^ (ly1 & 31));
            unsigned e11 = ly1 * 128 + (lx1 ^ (ly1 & 31));
            ttab[ai * NPIX + px] = make_uint4(e00 | (e10 << 16), e01 | (e11 << 16),
                                              q16(w00) | (q16(w10) << 16),
                                              q16(w01) | (q16(w11) << 16));
        } else {
            unsigned e00 = ly0 * 128 + ((((lx0 >> 1) ^ (ly0 & 31)) << 1) | (lx0 & 1));
            unsigned e10 = ly0 * 128 + ((((lx1 >> 1) ^ (ly0 & 31)) << 1) | (lx1 & 1));
            unsigned e01 = ly1 * 128 + ((((lx0 >> 1) ^ (ly1 & 31)) << 1) | (lx0 & 1));
            unsigned e11 = ly1 * 128 + ((((lx1 >> 1) ^ (ly1 & 31)) << 1) | (lx1 & 1));
            oinv[ai * NPIX + px] = make_uint2(e00 | (e10 << 16), e01 | (e11 << 16));
        }
    }
}

// Kernel 1: whole-plane rotate. Stage 128x128 fp32 (swizzled, 64 KB) coalesced,
// table-driven 4-tap gather, write bf16 xr + per-plane sum.
__global__ __launch_bounds__(512) void k_rotate(const float* __restrict__ x,
                                                const uint4* __restrict__ ttab, int ai,
                                                __hip_bfloat16* __restrict__ xr,
                                                float* __restrict__ p_sum) {
    __shared__ float lds[NPIX];          // 64 KB
    int plane = blockIdx.x;
    int t = threadIdx.x;
    const float* img = x + (size_t)plane * NPIX;
    #pragma unroll
    for (int i = 0; i < 32; ++i) {
        int w = (i << 9) + t;
        int r = w >> 7, cc = w & 127;
        lds[r * 128 + (cc ^ (r & 31))] = img[w];
    }
    __syncthreads();

    const uint4* tt = ttab + (size_t)ai * NPIX;
    __hip_bfloat16* op = xr + (size_t)plane * NPIX;
    float lsum = 0.f;
    #pragma unroll 4
    for (int i = 0; i < 32; ++i) {
        int px = (i << 9) + t;
        uint4 q = tt[px];
        float l0 = lds[q.x & 0xffff], l1 = lds[q.x >> 16];
        float l2 = lds[q.y & 0xffff], l3 = lds[q.y >> 16];
        float v = ((float)(q.z & 0xffff) * l0 + (float)(q.z >> 16) * l1
                 + (float)(q.w & 0xffff) * l2 + (float)(q.w >> 16) * l3) * (1.f / 65535.f);
        op[px] = __float2bfloat16(v);
        lsum += v;
    }
    for (int off = 32; off; off >>= 1) lsum += __shfl_down(lsum, off, 64);
    __syncthreads();                     // gather reads done; reuse lds for reduce
    if ((t & 63) == 0) lds[t >> 6] = lsum;
    __syncthreads();
    if (t == 0) {
        float s = 0.f;
        for (int k = 0; k < 8; ++k) s += lds[k];
        p_sum[plane] = s;
    }
}

// Kernel 2: tiny MLP. One block per batch.
__global__ void k_mlp(const float* __restrict__ p_sum, const float* __restrict__ w1,
                      const float* __restrict__ g, const float* __restrict__ be,
                      const float* __restrict__ mu, const float* __restrict__ var,
                      const float* __restrict__ w2, float* __restrict__ ca) {
    __shared__ float sp[CC];
    __shared__ float sh[MID];
    int b = blockIdx.x;
    int t = threadIdx.x;
    sp[t] = p_sum[b * CC + t] * (1.0f / (float)NPIX);
    __syncthreads();

    int m = t >> 2, q = t & 3;
    const float* w1r = w1 + m * CC + (q << 6);
    const float* spq = sp + (q << 6);
    float a = 0.f;
    for (int k = 0; k < 64; ++k) a += spq[k] * w1r[k];
    a += __shfl_xor(a, 1, 64);
    a += __shfl_xor(a, 2, 64);
    if (q == 0) {
        a = (a - mu[m]) * rsqrtf(var[m] + BN_EPS) * g[m] + be[m];
        sh[m] = fmaxf(a, 0.f);
    }
    __syncthreads();

    const float* w2r = w2 + t * MID;
    float a2 = 0.f;
    for (int k = 0; k < MID; ++k) a2 += sh[k] * w2r[k];
    ca[b * CC + t] = 1.f / (1.f + expf(-a2));
}

// Kernel 3: per-pixel channel avg & max of fca = xr * ca (4-way channel split).
__global__ void k_chanstat(const __hip_bfloat16* __restrict__ xr, const float* __restrict__ ca,
                           float* __restrict__ avg, float* __restrict__ mx) {
    __shared__ float rs0[4][64], rs1[4][64], rm0[4][64], rm1[4][64];
    int b    = blockIdx.x >> 7;
    int grp  = blockIdx.x & 127;
    int lane = threadIdx.x & 63;
    int cg   = threadIdx.x >> 6;
    int pp   = (grp << 6) + lane;

    const unsigned* xp = (const unsigned*)(xr + (size_t)b * CC * NPIX) + pp
                       + (size_t)(cg << 6) * (NPIX / 2);
    const float* cab = ca + b * CC + (cg << 6);

    float s0 = 0.f, s1 = 0.f, m0 = -INFINITY, m1 = -INFINITY;
    for (int ch = 0; ch < 64; ++ch) {
        unsigned u = xp[(size_t)ch * (NPIX / 2)];
        float v0 = __uint_as_float(u << 16);
        float v1 = __uint_as_float(u & 0xffff0000u);
        float cc = cab[ch];
        v0 *= cc; v1 *= cc;
        s0 += v0; s1 += v1;
        m0 = fmaxf(m0, v0); m1 = fmaxf(m1, v1);
    }
    rs0[cg][lane] = s0; rs1[cg][lane] = s1;
    rm0[cg][lane] = m0; rm1[cg][lane] = m1;
    __syncthreads();
    if (threadIdx.x < 64) {
        int l = threadIdx.x;
        float a0 = rs0[0][l] + rs0[1][l] + rs0[2][l] + rs0[3][l];
        float a1 = rs1[0][l] + rs1[1][l] + rs1[2][l] + rs1[3][l];
        float b0 = fmaxf(fmaxf(rm0[0][l], rm0[1][l]), fmaxf(rm0[2][l], rm0[3][l]));
        float b1 = fmaxf(fmaxf(rm1[0][l], rm1[1][l]), fmaxf(rm1[2][l], rm1[3][l]));
        float2* ap = (float2*)(avg + b * NPIX);
        float2* mp = (float2*)(mx + b * NPIX);
        int oidx = (grp << 6) + l;
        ap[oidx] = make_float2(a0 * (1.0f / (float)CC), a1 * (1.0f / (float)CC));
        mp[oidx] = make_float2(b0, b1);
    }
}

// Kernel 4: 7x7 conv (2 in-ch -> 1), pad 3, sigmoid -> sa.
__global__ void k_conv(const float* __restrict__ avg, const float* __restrict__ mx,
                       const float* __restrict__ w_sp, float* __restrict__ sa) {
    __shared__ float w[98];
    int t = threadIdx.x;
    if (t < 98) w[t] = w_sp[t];
    __syncthreads();
    int b = blockIdx.x >> 6;
    int pix = ((blockIdx.x & 63) << 8) + t;
    int yy = pix >> 7, xx = pix & (WW - 1);
    const float* a0 = avg + b * NPIX;
    const float* a1 = mx + b * NPIX;
    float acc = 0.f;
    for (int ky = 0; ky < 7; ++ky) {
        int ys = yy + ky - 3;
        if ((unsigned)ys >= HH) continue;
        for (int kx = 0; kx < 7; ++kx) {
            int xs = xx + kx - 3;
            if ((unsigned)xs >= WW) continue;
            acc += a0[ys * WW + xs] * w[ky * 7 + kx] + a1[ys * WW + xs] * w[49 + ky * 7 + kx];
        }
    }
    sa[b * NPIX + pix] = 1.f / (1.f + expf(-acc));
}

// Kernel 4b: fold sa into inverse-rotation weights, once per (batch, pixel).
// wf_i = w_i * sa[s_i], u16-packed. Channel-invariant -> removes all sa work
// from the 2048-plane invrot kernels.
__global__ __launch_bounds__(512) void k_wfold(const float* __restrict__ angles, int ai,
                                               const float* __restrict__ sa,
                                               uint2* __restrict__ wf) {
    int b  = blockIdx.x >> 5;
    int px = ((blockIdx.x & 31) << 9) + threadIdx.x;
    float ang = angles[ai];
    float c = cosf(ang), s = -sinf(ang);
    int yy = px >> 7, xx = px & 127;
    float w00, w10, w01, w11; int lx0, lx1, ly0, ly1;
    taps(xx, yy, c, s, w00, w10, w01, w11, lx0, lx1, ly0, ly1);
    const float* sb = sa + b * NPIX;
    float f00 = w00 * sb[ly0 * WW + lx0];
    float f10 = w10 * sb[ly0 * WW + lx1];
    float f01 = w01 * sb[ly1 * WW + lx0];
    float f11 = w11 * sb[ly1 * WW + lx1];
    wf[(size_t)b * NPIX + px] = make_uint2(q16(f00) | (q16(f10) << 16),
                                           q16(f01) | (q16(f11) << 16));
}

__device__ __forceinline__ float bf16_at(const unsigned* lds, unsigned e) {
    unsigned wd = lds[e >> 1];
    return __uint_as_float((e & 1) ? (wd & 0xffff0000u) : (wd << 16));
}

// Kernel 5a (pair-fused, whole-plane): inverse-rotate TWO angles, one out write.
__global__ __launch_bounds__(512) void k_invrot2(
        const __hip_bfloat16* __restrict__ xrA, const __hip_bfloat16* __restrict__ xrB,
        const float* __restrict__ caA, const float* __restrict__ caB,
        const uint2* __restrict__ oinv, const uint2* __restrict__ wfA,
        const uint2* __restrict__ wfB, int a0, int a1, int first,
        float* __restrict__ out) {
    __shared__ unsigned lds[2][NPIX / 2];    // 2 x 32 KB bf16 planes (u32 pairs)
    int plane = blockIdx.x;
    int b = plane >> 8;
    int t = threadIdx.x;
    const unsigned* pA = (const unsigned*)(xrA + (size_t)plane * NPIX);
    const unsigned* pB = (const unsigned*)(xrB + (size_t)plane * NPIX);
    #pragma unroll
    for (int i = 0; i < 16; ++i) {
        int w = (i << 9) + t;
        int r = w >> 6, cw = w & 63;
        int d = r * 64 + (cw ^ (r & 31));
        lds[0][d] = pA[w];
        lds[1][d] = pB[w];
    }
    __syncthreads();

    float scA = caA[plane] * (0.25f / 65535.f);
    float scB = caB[plane] * (0.25f / 65535.f);
    const uint2* oA = oinv + (size_t)a0 * NPIX;
    const uint2* oB = oinv + (size_t)a1 * NPIX;
    const uint2* fA = wfA + (size_t)b * NPIX;
    const uint2* fB = wfB + (size_t)b * NPIX;
    float* op = out + (size_t)plane * NPIX;
    #pragma unroll 4
    for (int i = 0; i < 32; ++i) {
        int px = (i << 9) + t;
        uint2 ea = oA[px], fa = fA[px];
        uint2 eb = oB[px], fb = fB[px];
        float vA = (float)(fa.x & 0xffff) * bf16_at(lds[0], ea.x & 0xffff)
                 + (float)(fa.x >> 16)    * bf16_at(lds[0], ea.x >> 16)
                 + (float)(fa.y & 0xffff) * bf16_at(lds[0], ea.y & 0xffff)
                 + (float)(fa.y >> 16)    * bf16_at(lds[0], ea.y >> 16);
        float vB = (float)(fb.x & 0xffff) * bf16_at(lds[1], eb.x & 0xffff)
                 + (float)(fb.x >> 16)    * bf16_at(lds[1], eb.x >> 16)
                 + (float)(fb.y & 0xffff) * bf16_at(lds[1], eb.y & 0xffff)
                 + (float)(fb.y >> 16)    * bf16_at(lds[1], eb.y >> 16);
        float v = scA * vA + scB * vB;
        if (first) op[px] = v;
        else       op[px] += v;
    }
}

// Kernel 5b (fallback, single angle, whole-plane).
__global__ __launch_bounds__(512) void k_invrot1(
        const __hip_bfloat16* __restrict__ xr, const float* __restrict__ ca,
        const uint2* __restrict__ oinv, const uint2* __restrict__ wfA,
        int ai, int first, float* __restrict__ out) {
    __shared__ unsigned lds[NPIX / 2];       // 32 KB
    int plane = blockIdx.x;
    int b = plane >> 8;
    int t = threadIdx.x;
    const unsigned* pA = (const unsigned*)(xr + (size_t)plane * NPIX);
    #pragma unroll
    for (int i = 0; i < 16; ++i) {
        int w = (i << 9) + t;
        int r = w >> 6, cw = w & 63;
        lds[r * 64 + (cw ^ (r & 31))] = pA[w];
    }
    __syncthreads();

    float scA = ca[plane] * (0.25f / 65535.f);
    const uint2* oA = oinv + (size_t)ai * NPIX;
    const uint2* fA = wfA + (size_t)b * NPIX;
    float* op = out + (size_t)plane * NPIX;
    #pragma unroll 4
    for (int i = 0; i < 32; ++i) {
        int px = (i << 9) + t;
        uint2 ea = oA[px], fa = fA[px];
        float vA = (float)(fa.x & 0xffff) * bf16_at(lds, ea.x & 0xffff)
                 + (float)(fa.x >> 16)    * bf16_at(lds, ea.x >> 16)
                 + (float)(fa.y & 0xffff) * bf16_at(lds, ea.y & 0xffff)
                 + (float)(fa.y >> 16)    * bf16_at(lds, ea.y >> 16);
        float v = scA * vA;
        if (first) op[px] = v;
        else       op[px] += v;
    }
}

extern "C" void kernel_launch(void* const* d_in, const int* in_sizes, int n_in,
                              void* d_out, int out_size, void* d_ws, size_t ws_size,
                              hipStream_t stream) {
    const float* x      = (const float*)d_in[0];
    const float* angles = (const float*)d_in[1];
    const float* w1     = (const float*)d_in[2];
    const float* gmm    = (const float*)d_in[3];
    const float* bet    = (const float*)d_in[4];
    const float* mu     = (const float*)d_in[5];
    const float* var    = (const float*)d_in[6];
    const float* w2     = (const float*)d_in[7];
    const float* wsp    = (const float*)d_in[8];
    float* out = (float*)d_out;

    char* ws = (char*)d_ws;
    uint4* ttab  = (uint4*)ws;                        // 4*16384*16 B = 1 MiB
    uint2* oinv  = (uint2*)(ttab + 4 * NPIX);         // 512 KiB
    float* p_sum = (float*)(oinv + 4 * NPIX);         // 8 KiB
    float* caA   = p_sum + BB * CC;
    float* caB   = caA + BB * CC;
    float* avg   = caB + BB * CC;                     // 512 KiB
    float* mxp   = avg + BB * NPIX;                   // 512 KiB
    float* saA   = mxp + BB * NPIX;                   // 512 KiB
    float* saB   = saA + BB * NPIX;                   // 512 KiB
    uint2* wfA   = (uint2*)(saB + BB * NPIX);         // 1 MiB
    uint2* wfB   = wfA + BB * NPIX;                   // 1 MiB
    __hip_bfloat16* xrA = (__hip_bfloat16*)(wfB + BB * NPIX);   // 64 MiB
    __hip_bfloat16* xrB = xrA + (size_t)BB * CC * NPIX;         // 64 MiB
    size_t need_pair = (size_t)((char*)(xrB + (size_t)BB * CC * NPIX) - ws);

    k_tables<<<8, 512, 0, stream>>>(angles, ttab, oinv);

    if (ws_size >= need_pair) {
        for (int pr = 0; pr < 2; ++pr) {
            int a0 = pr * 2, a1 = a0 + 1;
            k_rotate  <<<BB * CC, 512, 0, stream>>>(x, ttab, a0, xrA, p_sum);
            k_mlp     <<<BB, 256, 0, stream>>>(p_sum, w1, gmm, bet, mu, var, w2, caA);
            k_chanstat<<<BB * 128, 256, 0, stream>>>(xrA, caA, avg, mxp);
            k_conv    <<<BB * 64, 256, 0, stream>>>(avg, mxp, wsp, saA);
            k_wfold   <<<BB * 32, 512, 0, stream>>>(angles, a0, saA, wfA);
            k_rotate  <<<BB * CC, 512, 0, stream>>>(x, ttab, a1, xrB, p_sum);
            k_mlp     <<<BB, 256, 0, stream>>>(p_sum, w1, gmm, bet, mu, var, w2, caB);
            k_chanstat<<<BB * 128, 256, 0, stream>>>(xrB, caB, avg, mxp);
            k_conv    <<<BB * 64, 256, 0, stream>>>(avg, mxp, wsp, saB);
            k_wfold   <<<BB * 32, 512, 0, stream>>>(angles, a1, saB, wfB);
            k_invrot2 <<<BB * CC, 512, 0, stream>>>(xrA, xrB, caA, caB, oinv, wfA, wfB,
                                                    a0, a1, pr == 0, out);
        }
    } else {
        for (int ai = 0; ai < 4; ++ai) {
            k_rotate  <<<BB * CC, 512, 0, stream>>>(x, ttab, ai, xrA, p_sum);
            k_mlp     <<<BB, 256, 0, stream>>>(p_sum, w1, gmm, bet, mu, var, w2, caA);
            k_chanstat<<<BB * 128, 256, 0, stream>>>(xrA, caA, avg, mxp);
            k_conv    <<<BB * 64, 256, 0, stream>>>(avg, mxp, wsp, saA);
            k_wfold   <<<BB * 32, 512, 0, stream>>>(angles, ai, saA, wfA);
            k_invrot1 <<<BB * CC, 512, 0, stream>>>(xrA, caA, oinv, wfA, ai, ai == 0, out);
        }
    }
}